// Round 13
// baseline (316.949 us; speedup 1.0000x reference)
//
#include <hip/hip_runtime.h>

typedef __bf16 bf16x8 __attribute__((ext_vector_type(8)));
typedef float f32x4 __attribute__((ext_vector_type(4)));

#define LDK 72  // P-strip LDS row stride (elements)
#define LOG2E 1.44269504088896f

__device__ __forceinline__ unsigned short bfbits(float x) {
  __bf16 h = (__bf16)x;  // native v_cvt RNE on gfx950
  return __builtin_bit_cast(unsigned short, h);
}

// async global->LDS, 16B per lane. LDS dest = wave-uniform base + lane*16 (m104/m108).
__device__ __forceinline__ void gload_lds16(const unsigned short* g, unsigned short* l) {
  __builtin_amdgcn_global_load_lds(
      (const __attribute__((address_space(1))) unsigned int*)(const void*)g,
      (__attribute__((address_space(3))) unsigned int*)(void*)l, 16, 0, 0);
}

// ---- fused prelude: [0,2048) hid fp32->bf16 | [2048,3072) W transpose | [3072,3328) bias ----
__global__ __launch_bounds__(256)
void prelude_kernel(const float* __restrict__ hidden, unsigned short* __restrict__ hid_bf,
                    const float* __restrict__ W0, const float* __restrict__ W1,
                    const float* __restrict__ W2, const float* __restrict__ W3,
                    unsigned short* __restrict__ T0, unsigned short* __restrict__ T1,
                    unsigned short* __restrict__ T2, unsigned short* __restrict__ T3,
                    const float* __restrict__ rel_emb, float* __restrict__ bias_tab) {
  __shared__ __align__(16) unsigned short Tlds[64 * 68];
  const int bx = blockIdx.x, tid = threadIdx.x;
  if (bx < 2048) {
    int idx = (bx * 256 + tid) * 8;
    float4 v0 = *(const float4*)(hidden + idx);
    float4 v1 = *(const float4*)(hidden + idx + 4);
    unsigned short o[8] = {bfbits(v0.x), bfbits(v0.y), bfbits(v0.z), bfbits(v0.w),
                           bfbits(v1.x), bfbits(v1.y), bfbits(v1.z), bfbits(v1.w)};
    *(uint4*)(hid_bf + idx) = *(const uint4*)o;
  } else if (bx < 3072) {
    int flat = bx - 2048;
    int mz = flat >> 8;
    int k0 = ((flat >> 4) & 15) * 64, n0 = (flat & 15) * 64;
    const float* W = mz == 0 ? W0 : (mz == 1 ? W1 : (mz == 2 ? W2 : W3));
    unsigned short* T = mz == 0 ? T0 : (mz == 1 ? T1 : (mz == 2 ? T2 : T3));
#pragma unroll
    for (int p = 0; p < 4; ++p) {
      int idx = p * 256 + tid;
      int kk = idx >> 4, nc = idx & 15;
      float4 v = *(const float4*)(W + (size_t)(k0 + kk) * 1024 + n0 + nc * 4);
      ushort4 s;
      s.x = bfbits(v.x); s.y = bfbits(v.y); s.z = bfbits(v.z); s.w = bfbits(v.w);
      *(ushort4*)(Tlds + kk * 68 + nc * 4) = s;
    }
    __syncthreads();
#pragma unroll
    for (int p = 0; p < 2; ++p) {
      int idx = p * 256 + tid;
      int n = idx >> 3, c = idx & 7;
      unsigned short tmp[8];
#pragma unroll
      for (int j = 0; j < 8; ++j) tmp[j] = Tlds[(c * 8 + j) * 68 + n];
      *(uint4*)(T + (size_t)(n0 + n) * 1024 + k0 + c * 8) = *(const uint4*)tmp;
    }
  } else {
    int i = (bx - 3072) * 256 + tid;  // 0..65535
    int h = i >> 12;
    int idx = i & 4095;
    int rp = idx - 2048;
    int base = (rp > 0) ? 16 : 0;
    int rel = rp < 0 ? -rp : rp;
    int b;
    if (rel < 8) {
      b = rel;
    } else {
      b = 8 + (int)(log2f((float)rel * 0.125f) * 2.0f);  // == int(log(rel/8)/log(16)*8)
      if (b > 15) b = 15;
    }
    bias_tab[h * 4096 + idx] = rel_emb[(base + b) * 16 + h] * LOG2E - 64.0f;
  }
}

// ------- GEMM with register-prefetch pipeline + XOR-swizzled LDS --------------------
// Per kt: barrier1 (drains prev prefetch vmcnt) -> ds_write regs -> barrier2 (lgkm only,
// no vmem outstanding) -> issue prefetch kt+1 -> compute kt.
// __launch_bounds__(256, 2): min 2 waves/EU -> 256-VGPR cap -> prefetch regs stay in
// registers (round-12 default cap of 80 spilled them to scratch: 270 MB WRITE_SIZE).
template <bool OUT_F32, int BN>
__global__ __launch_bounds__(256, 2)
void gemm_kernel(const unsigned short* __restrict__ A,
                 const unsigned short* __restrict__ Wt0,
                 const unsigned short* __restrict__ Wt1,
                 const unsigned short* __restrict__ Wt2,
                 void* __restrict__ O0v, void* __restrict__ O1v, void* __restrict__ O2v,
                 float scale0) {
  constexpr int NBLK = 1024 / BN;
  constexpr int NT = BN / 32;
  __shared__ __align__(16) unsigned short Alds[128 * 64];
  __shared__ __align__(16) unsigned short Wlds[BN * 64];
  const int tid = threadIdx.x;
  const int which = blockIdx.x / NBLK;
  const int n0 = (blockIdx.x % NBLK) * BN;
  const int m0 = blockIdx.y * 128;
  const unsigned short* Wt = which == 0 ? Wt0 : (which == 1 ? Wt1 : Wt2);
  void* Ov = which == 0 ? O0v : (which == 1 ? O1v : O2v);
  const int wave = tid >> 6, lane = tid & 63, quad = lane >> 4, col = lane & 15;
  const int wm = (wave >> 1) * 64, wn = (wave & 1) * (BN / 2);
  const int sw = col & 7;

  f32x4 acc[4][NT] = {};
  uint4 pa[4], pw[NT];

  const int am[4] = {(0 * 256 + tid) >> 3, (1 * 256 + tid) >> 3,
                     (2 * 256 + tid) >> 3, (3 * 256 + tid) >> 3};
  const int ac = tid & 7;

  auto prefetch = [&](int kt) {
    const int k0 = kt * 64;
#pragma unroll
    for (int p = 0; p < 4; ++p)
      pa[p] = *(const uint4*)(A + (size_t)(m0 + am[p]) * 1024 + k0 + ac * 8);
#pragma unroll
    for (int p = 0; p < NT; ++p)
      pw[p] = *(const uint4*)(Wt + (size_t)(n0 + am[p]) * 1024 + k0 + ac * 8);
  };

  prefetch(0);

  for (int kt = 0; kt < 16; ++kt) {
    __syncthreads();  // drains prefetch vmcnt (issued a full compute phase ago)
#pragma unroll
    for (int p = 0; p < 4; ++p)
      *(uint4*)(Alds + am[p] * 64 + (ac ^ (am[p] & 7)) * 8) = pa[p];
#pragma unroll
    for (int p = 0; p < NT; ++p)
      *(uint4*)(Wlds + am[p] * 64 + (ac ^ (am[p] & 7)) * 8) = pw[p];
    __syncthreads();  // no vmem outstanding here -> cheap
    if (kt + 1 < 16) prefetch(kt + 1);
#pragma unroll
    for (int ks = 0; ks < 2; ++ks) {
      bf16x8 af[4], wf[NT];
#pragma unroll
      for (int mt = 0; mt < 4; ++mt)
        af[mt] = *(const bf16x8*)(Alds + (wm + mt * 16 + col) * 64 +
                                  (((ks * 4 + quad) ^ sw) * 8));
#pragma unroll
      for (int nt = 0; nt < NT; ++nt)
        wf[nt] = *(const bf16x8*)(Wlds + (wn + nt * 16 + col) * 64 +
                                  (((ks * 4 + quad) ^ sw) * 8));
#pragma unroll
      for (int mt = 0; mt < 4; ++mt)
#pragma unroll
        for (int nt = 0; nt < NT; ++nt)
          acc[mt][nt] = __builtin_amdgcn_mfma_f32_16x16x32_bf16(af[mt], wf[nt], acc[mt][nt], 0, 0, 0);
    }
  }
  if (!OUT_F32 && which == 2) {
    unsigned short* Ot = (unsigned short*)Ov;  // V transposed: Vt[n][token]
#pragma unroll
    for (int nt = 0; nt < NT; ++nt)
#pragma unroll
      for (int mt = 0; mt < 4; ++mt) {
        int n = n0 + wn + nt * 16 + col;
        int m = m0 + wm + mt * 16 + quad * 4;
        ushort4 s;
        s.x = bfbits(acc[mt][nt][0]); s.y = bfbits(acc[mt][nt][1]);
        s.z = bfbits(acc[mt][nt][2]); s.w = bfbits(acc[mt][nt][3]);
        *(ushort4*)(Ot + (size_t)n * 4096 + m) = s;
      }
  } else {
    const float sc = (which == 0) ? scale0 : 1.0f;
#pragma unroll
    for (int mt = 0; mt < 4; ++mt)
#pragma unroll
      for (int nt = 0; nt < NT; ++nt)
#pragma unroll
        for (int r = 0; r < 4; ++r) {
          int m = m0 + wm + mt * 16 + quad * 4 + r;
          int n = n0 + wn + nt * 16 + col;
          float x = acc[mt][nt][r] * sc;
          if (OUT_F32)
            ((float*)Ov)[(size_t)m * 1024 + n] = x;
          else
            ((unsigned short*)Ov)[(size_t)m * 1024 + n] = bfbits(x);
        }
  }
}

// ---- flash attention: S^T form, fixed-max softmax, far-tile bias splat,
// dbuf DMA K/V staging, l computed via MFMA (P · ones) ----
__global__ __launch_bounds__(256)
void attn_kernel(unsigned short* __restrict__ q_ws,
                 const unsigned short* __restrict__ k_ws,
                 const unsigned short* __restrict__ vt_ws,
                 const float* __restrict__ bias_tab) {
  __shared__ __align__(16) unsigned short Klds[2][64 * 64];  // [key][d], swizzled
  __shared__ __align__(16) unsigned short Vlds[2][64 * 64];  // [d][key], swizzled
  __shared__ __align__(16) unsigned short Plds[128 * LDK];   // [q][key], wave-private
  __shared__ float bias_lds[2][192];
  const int tid = threadIdx.x;
  const int q0 = blockIdx.x * 128;
  const int bh = blockIdx.y;
  const int b = bh >> 4, h = bh & 15;
  const int wave = tid >> 6, lane = tid & 63, quad = lane >> 4, col = lane & 15;
  const int wbase = tid & ~63;
  const int sw = col & 7;

  bf16x8 qf[2][2];
#pragma unroll
  for (int nt = 0; nt < 2; ++nt) {
    size_t row = (size_t)(b * 2048 + q0 + wave * 32 + nt * 16 + col) * 1024 + h * 64;
    qf[nt][0] = *(const bf16x8*)(q_ws + row + quad * 8);
    qf[nt][1] = *(const bf16x8*)(q_ws + row + 32 + quad * 8);
  }
  const float bias_far_pos = bias_tab[h * 4096 + 2048 + 512];
  const float bias_far_neg = bias_tab[h * 4096 + 2048 - 512];

  bf16x8 vone;
#pragma unroll
  for (int j = 0; j < 8; ++j) vone[j] = (__bf16)1.0f;

  f32x4 of[2][4] = {};
  f32x4 l_acc[2] = {};  // l via MFMA: rows match of[] layout, cols redundant

  auto stage = [&](int kt, int buf) {
    const int k0 = kt * 64;
#pragma unroll
    for (int p = 0; p < 2; ++p) {
      int idx = p * 256 + tid;
      int key = idx >> 3, c = idx & 7;
      int cs = c ^ (key & 7);
      gload_lds16(k_ws + (size_t)(b * 2048 + k0 + key) * 1024 + h * 64 + cs * 8,
                  Klds[buf] + (size_t)(p * 256 + wbase) * 8);
    }
#pragma unroll
    for (int p = 0; p < 2; ++p) {
      int idx = p * 256 + tid;
      int d = idx >> 3, c = idx & 7;
      int cs = c ^ (d & 7);
      gload_lds16(vt_ws + (size_t)(h * 64 + d) * 4096 + b * 2048 + k0 + cs * 8,
                  Vlds[buf] + (size_t)(p * 256 + wbase) * 8);
    }
    const int diff = k0 - q0;
    const bool farr = (diff >= 256) || (diff <= -192);
    if (!farr && tid < 191)
      bias_lds[buf][tid] = bias_tab[h * 4096 + 2048 + k0 - q0 - 127 + tid];
  };

  stage(0, 0);

  for (int kt = 0; kt < 32; ++kt) {
    const int cur = kt & 1;
    const int k0 = kt * 64;
    const int diff = k0 - q0;
    const bool far = (diff >= 256) || (diff <= -192);
    __syncthreads();  // buf[cur] DMA (issued a full compute phase ago) drains here
    if (kt + 1 < 32) stage(kt + 1, cur ^ 1);

    // S^T = K·Q^T + bias (bias as C-init)
    f32x4 st[4][2];
    if (far) {
      const float c0 = (diff > 0) ? bias_far_pos : bias_far_neg;
#pragma unroll
      for (int mt = 0; mt < 4; ++mt)
#pragma unroll
        for (int nt = 0; nt < 2; ++nt)
#pragma unroll
          for (int r = 0; r < 4; ++r) st[mt][nt][r] = c0;
    } else {
#pragma unroll
      for (int mt = 0; mt < 4; ++mt)
#pragma unroll
        for (int nt = 0; nt < 2; ++nt)
#pragma unroll
          for (int r = 0; r < 4; ++r)
            st[mt][nt][r] =
                bias_lds[cur][(mt * 16 + quad * 4 + r) - (wave * 32 + nt * 16 + col) + 127];
    }
#pragma unroll
    for (int ks = 0; ks < 2; ++ks)
#pragma unroll
      for (int mt = 0; mt < 4; ++mt) {
        bf16x8 kf = *(const bf16x8*)(Klds[cur] + (mt * 16 + col) * 64 +
                                     (((ks * 4 + quad) ^ sw) * 8));
        st[mt][0] = __builtin_amdgcn_mfma_f32_16x16x32_bf16(kf, qf[0][ks], st[mt][0], 0, 0, 0);
        st[mt][1] = __builtin_amdgcn_mfma_f32_16x16x32_bf16(kf, qf[1][ks], st[mt][1], 0, 0, 0);
      }

    // p = exp2(st); pack 4 keys -> ds_write_b64 into P[q][key]
#pragma unroll
    for (int nt = 0; nt < 2; ++nt)
#pragma unroll
      for (int mt = 0; mt < 4; ++mt) {
        float p0 = __builtin_amdgcn_exp2f(st[mt][nt][0]);
        float p1 = __builtin_amdgcn_exp2f(st[mt][nt][1]);
        float p2 = __builtin_amdgcn_exp2f(st[mt][nt][2]);
        float p3 = __builtin_amdgcn_exp2f(st[mt][nt][3]);
        ushort4 pk;
        pk.x = bfbits(p0); pk.y = bfbits(p1); pk.z = bfbits(p2); pk.w = bfbits(p3);
        *(ushort4*)(Plds + (wave * 32 + nt * 16 + col) * LDK + mt * 16 + quad * 4) = pk;
      }
    __threadfence_block();  // wave-private strips: compiler+lgkmcnt fence suffices

    // O += P·V ; l += P·1 (same bf16 P for both -> normalization errors cancel)
#pragma unroll
    for (int ks = 0; ks < 2; ++ks) {
      bf16x8 pf0 = *(const bf16x8*)(Plds + (wave * 32 + col) * LDK + ks * 32 + quad * 8);
      bf16x8 pf1 = *(const bf16x8*)(Plds + (wave * 32 + 16 + col) * LDK + ks * 32 + quad * 8);
      l_acc[0] = __builtin_amdgcn_mfma_f32_16x16x32_bf16(pf0, vone, l_acc[0], 0, 0, 0);
      l_acc[1] = __builtin_amdgcn_mfma_f32_16x16x32_bf16(pf1, vone, l_acc[1], 0, 0, 0);
#pragma unroll
      for (int dn = 0; dn < 4; ++dn) {
        bf16x8 vf = *(const bf16x8*)(Vlds[cur] + (dn * 16 + col) * 64 +
                                     (((ks * 4 + quad) ^ sw) * 8));
        of[0][dn] = __builtin_amdgcn_mfma_f32_16x16x32_bf16(pf0, vf, of[0][dn], 0, 0, 0);
        of[1][dn] = __builtin_amdgcn_mfma_f32_16x16x32_bf16(pf1, vf, of[1][dn], 0, 0, 0);
      }
    }
  }

  // epilogue: l_acc rows match of[] rows (no shuffles / LDS / barrier needed)
#pragma unroll
  for (int mtp = 0; mtp < 2; ++mtp)
#pragma unroll
    for (int r = 0; r < 4; ++r) {
      float inv = 1.0f / fmaxf(l_acc[mtp][r], 1e-30f);
      size_t row = (size_t)(b * 2048 + q0 + wave * 32 + mtp * 16 + quad * 4 + r);
#pragma unroll
      for (int dn = 0; dn < 4; ++dn)
        q_ws[row * 1024 + h * 64 + dn * 16 + col] = bfbits(of[mtp][dn][r] * inv);
    }
}

extern "C" void kernel_launch(void* const* d_in, const int* in_sizes, int n_in,
                              void* d_out, int out_size, void* d_ws, size_t ws_size,
                              hipStream_t stream) {
  const float* hidden = (const float*)d_in[0];
  const float* Wq = (const float*)d_in[1];
  const float* Wk = (const float*)d_in[2];
  const float* Wv = (const float*)d_in[3];
  const float* Wo = (const float*)d_in[4];
  const float* rel_emb = (const float*)d_in[5];
  float* out = (float*)d_out;

  unsigned short* q_ws = (unsigned short*)d_ws;  // 8 MB; Q (x log2e), then attn output
  unsigned short* k_ws = q_ws + 4194304;         // 8 MB
  unsigned short* vt_ws = k_ws + 4194304;        // 8 MB, V transposed [h*64+d][token]
  unsigned short* wt_q = vt_ws + 4194304;        // 2 MB Wt[n][k] bf16
  unsigned short* wt_k = wt_q + 1048576;         // 2 MB
  unsigned short* wt_v = wt_k + 1048576;         // 2 MB
  unsigned short* wt_o = wt_v + 1048576;         // 2 MB
  float* bias_tab = (float*)(wt_o + 1048576);    // 256 KB
  unsigned short* hid_bf = (unsigned short*)d_out;

  prelude_kernel<<<3328, 256, 0, stream>>>(hidden, hid_bf, Wq, Wk, Wv, Wo,
                                           wt_q, wt_k, wt_v, wt_o, rel_emb, bias_tab);
  gemm_kernel<false, 128><<<dim3(24, 32), 256, 0, stream>>>(
      hid_bf, wt_q, wt_k, wt_v, q_ws, k_ws, vt_ws, LOG2E);
  attn_kernel<<<dim3(16, 32), 256, 0, stream>>>(q_ws, k_ws, vt_ws, bias_tab);
  gemm_kernel<true, 64><<<dim3(16, 32), 256, 0, stream>>>(
      q_ws, wt_o, wt_o, wt_o, out, out, out, 1.0f);
}

// Round 14
// 195.863 us; speedup vs baseline: 1.6182x; 1.6182x over previous
//
#include <hip/hip_runtime.h>

typedef __bf16 bf16x8 __attribute__((ext_vector_type(8)));
typedef float f32x4 __attribute__((ext_vector_type(4)));

#define LDK 72  // P-strip LDS row stride (elements)
#define LOG2E 1.44269504088896f

__device__ __forceinline__ unsigned short bfbits(float x) {
  __bf16 h = (__bf16)x;  // native v_cvt RNE on gfx950
  return __builtin_bit_cast(unsigned short, h);
}

// async global->LDS, 16B per lane. LDS dest = wave-uniform base + lane*16 (m104/m108).
__device__ __forceinline__ void gload_lds16(const unsigned short* g, unsigned short* l) {
  __builtin_amdgcn_global_load_lds(
      (const __attribute__((address_space(1))) unsigned int*)(const void*)g,
      (__attribute__((address_space(3))) unsigned int*)(void*)l, 16, 0, 0);
}

// ---- fused prelude: [0,2048) hid fp32->bf16 | [2048,3072) W transpose | [3072,3328) bias ----
__global__ __launch_bounds__(256)
void prelude_kernel(const float* __restrict__ hidden, unsigned short* __restrict__ hid_bf,
                    const float* __restrict__ W0, const float* __restrict__ W1,
                    const float* __restrict__ W2, const float* __restrict__ W3,
                    unsigned short* __restrict__ T0, unsigned short* __restrict__ T1,
                    unsigned short* __restrict__ T2, unsigned short* __restrict__ T3,
                    const float* __restrict__ rel_emb, float* __restrict__ bias_tab) {
  __shared__ __align__(16) unsigned short Tlds[64 * 68];
  const int bx = blockIdx.x, tid = threadIdx.x;
  if (bx < 2048) {
    int idx = (bx * 256 + tid) * 8;
    float4 v0 = *(const float4*)(hidden + idx);
    float4 v1 = *(const float4*)(hidden + idx + 4);
    unsigned short o[8] = {bfbits(v0.x), bfbits(v0.y), bfbits(v0.z), bfbits(v0.w),
                           bfbits(v1.x), bfbits(v1.y), bfbits(v1.z), bfbits(v1.w)};
    *(uint4*)(hid_bf + idx) = *(const uint4*)o;
  } else if (bx < 3072) {
    int flat = bx - 2048;
    int mz = flat >> 8;
    int k0 = ((flat >> 4) & 15) * 64, n0 = (flat & 15) * 64;
    const float* W = mz == 0 ? W0 : (mz == 1 ? W1 : (mz == 2 ? W2 : W3));
    unsigned short* T = mz == 0 ? T0 : (mz == 1 ? T1 : (mz == 2 ? T2 : T3));
#pragma unroll
    for (int p = 0; p < 4; ++p) {
      int idx = p * 256 + tid;
      int kk = idx >> 4, nc = idx & 15;
      float4 v = *(const float4*)(W + (size_t)(k0 + kk) * 1024 + n0 + nc * 4);
      ushort4 s;
      s.x = bfbits(v.x); s.y = bfbits(v.y); s.z = bfbits(v.z); s.w = bfbits(v.w);
      *(ushort4*)(Tlds + kk * 68 + nc * 4) = s;
    }
    __syncthreads();
#pragma unroll
    for (int p = 0; p < 2; ++p) {
      int idx = p * 256 + tid;
      int n = idx >> 3, c = idx & 7;
      unsigned short tmp[8];
#pragma unroll
      for (int j = 0; j < 8; ++j) tmp[j] = Tlds[(c * 8 + j) * 68 + n];
      *(uint4*)(T + (size_t)(n0 + n) * 1024 + k0 + c * 8) = *(const uint4*)tmp;
    }
  } else {
    int i = (bx - 3072) * 256 + tid;  // 0..65535
    int h = i >> 12;
    int idx = i & 4095;
    int rp = idx - 2048;
    int base = (rp > 0) ? 16 : 0;
    int rel = rp < 0 ? -rp : rp;
    int b;
    if (rel < 8) {
      b = rel;
    } else {
      b = 8 + (int)(log2f((float)rel * 0.125f) * 2.0f);  // == int(log(rel/8)/log(16)*8)
      if (b > 15) b = 15;
    }
    bias_tab[h * 4096 + idx] = rel_emb[(base + b) * 16 + h] * LOG2E - 64.0f;
  }
}

// ------- GEMM (round-10/11 known-good): DMA global_load_lds staging + XOR swizzle ----
// Register-prefetch pipeline abandoned: rounds 12/13 showed the compiler keeps the
// prefetch arrays in scratch (VGPR=68-80, 270-320 MB spill WRITE_SIZE) regardless of
// __launch_bounds__. DMA staging measured clean: VGPR 68, no spill.
template <bool OUT_F32, int BN>
__global__ __launch_bounds__(256)
void gemm_kernel(const unsigned short* __restrict__ A,
                 const unsigned short* __restrict__ Wt0,
                 const unsigned short* __restrict__ Wt1,
                 const unsigned short* __restrict__ Wt2,
                 void* __restrict__ O0v, void* __restrict__ O1v, void* __restrict__ O2v,
                 float scale0) {
  constexpr int NBLK = 1024 / BN;
  constexpr int NT = BN / 32;
  __shared__ __align__(16) unsigned short Alds[128 * 64];
  __shared__ __align__(16) unsigned short Wlds[BN * 64];
  const int tid = threadIdx.x;
  const int which = blockIdx.x / NBLK;
  const int n0 = (blockIdx.x % NBLK) * BN;
  const int m0 = blockIdx.y * 128;
  const unsigned short* Wt = which == 0 ? Wt0 : (which == 1 ? Wt1 : Wt2);
  void* Ov = which == 0 ? O0v : (which == 1 ? O1v : O2v);
  const int wave = tid >> 6, lane = tid & 63, quad = lane >> 4, col = lane & 15;
  const int wm = (wave >> 1) * 64, wn = (wave & 1) * (BN / 2);
  const int wbase = tid & ~63;
  const int sw = col & 7;

  f32x4 acc[4][NT] = {};

  for (int kt = 0; kt < 16; ++kt) {
    const int k0 = kt * 64;
    __syncthreads();
#pragma unroll
    for (int p = 0; p < 4; ++p) {
      int idx = p * 256 + tid;
      int m = idx >> 3, c = idx & 7;
      int cs = c ^ (m & 7);
      gload_lds16(A + (size_t)(m0 + m) * 1024 + k0 + cs * 8,
                  Alds + (size_t)(p * 256 + wbase) * 8);
    }
#pragma unroll
    for (int p = 0; p < BN / 32; ++p) {
      int idx = p * 256 + tid;
      int n = idx >> 3, c = idx & 7;
      int cs = c ^ (n & 7);
      gload_lds16(Wt + (size_t)(n0 + n) * 1024 + k0 + cs * 8,
                  Wlds + (size_t)(p * 256 + wbase) * 8);
    }
    __syncthreads();
#pragma unroll
    for (int ks = 0; ks < 2; ++ks) {
      bf16x8 af[4], wf[NT];
#pragma unroll
      for (int mt = 0; mt < 4; ++mt)
        af[mt] = *(const bf16x8*)(Alds + (wm + mt * 16 + col) * 64 +
                                  (((ks * 4 + quad) ^ sw) * 8));
#pragma unroll
      for (int nt = 0; nt < NT; ++nt)
        wf[nt] = *(const bf16x8*)(Wlds + (wn + nt * 16 + col) * 64 +
                                  (((ks * 4 + quad) ^ sw) * 8));
#pragma unroll
      for (int mt = 0; mt < 4; ++mt)
#pragma unroll
        for (int nt = 0; nt < NT; ++nt)
          acc[mt][nt] = __builtin_amdgcn_mfma_f32_16x16x32_bf16(af[mt], wf[nt], acc[mt][nt], 0, 0, 0);
    }
  }
  if (!OUT_F32 && which == 2) {
    unsigned short* Ot = (unsigned short*)Ov;  // V transposed: Vt[n][token]
#pragma unroll
    for (int nt = 0; nt < NT; ++nt)
#pragma unroll
      for (int mt = 0; mt < 4; ++mt) {
        int n = n0 + wn + nt * 16 + col;
        int m = m0 + wm + mt * 16 + quad * 4;
        ushort4 s;
        s.x = bfbits(acc[mt][nt][0]); s.y = bfbits(acc[mt][nt][1]);
        s.z = bfbits(acc[mt][nt][2]); s.w = bfbits(acc[mt][nt][3]);
        *(ushort4*)(Ot + (size_t)n * 4096 + m) = s;
      }
  } else {
    const float sc = (which == 0) ? scale0 : 1.0f;
#pragma unroll
    for (int mt = 0; mt < 4; ++mt)
#pragma unroll
      for (int nt = 0; nt < NT; ++nt)
#pragma unroll
        for (int r = 0; r < 4; ++r) {
          int m = m0 + wm + mt * 16 + quad * 4 + r;
          int n = n0 + wn + nt * 16 + col;
          float x = acc[mt][nt][r] * sc;
          if (OUT_F32)
            ((float*)Ov)[(size_t)m * 1024 + n] = x;
          else
            ((unsigned short*)Ov)[(size_t)m * 1024 + n] = bfbits(x);
        }
  }
}

// ---- flash attention: S^T form, fixed-max softmax, far-tile bias splat,
// dbuf DMA K/V staging, l computed via MFMA (P · ones) ----
__global__ __launch_bounds__(256)
void attn_kernel(unsigned short* __restrict__ q_ws,
                 const unsigned short* __restrict__ k_ws,
                 const unsigned short* __restrict__ vt_ws,
                 const float* __restrict__ bias_tab) {
  __shared__ __align__(16) unsigned short Klds[2][64 * 64];  // [key][d], swizzled
  __shared__ __align__(16) unsigned short Vlds[2][64 * 64];  // [d][key], swizzled
  __shared__ __align__(16) unsigned short Plds[128 * LDK];   // [q][key], wave-private
  __shared__ float bias_lds[2][192];
  const int tid = threadIdx.x;
  const int q0 = blockIdx.x * 128;
  const int bh = blockIdx.y;
  const int b = bh >> 4, h = bh & 15;
  const int wave = tid >> 6, lane = tid & 63, quad = lane >> 4, col = lane & 15;
  const int wbase = tid & ~63;
  const int sw = col & 7;

  bf16x8 qf[2][2];
#pragma unroll
  for (int nt = 0; nt < 2; ++nt) {
    size_t row = (size_t)(b * 2048 + q0 + wave * 32 + nt * 16 + col) * 1024 + h * 64;
    qf[nt][0] = *(const bf16x8*)(q_ws + row + quad * 8);
    qf[nt][1] = *(const bf16x8*)(q_ws + row + 32 + quad * 8);
  }
  const float bias_far_pos = bias_tab[h * 4096 + 2048 + 512];
  const float bias_far_neg = bias_tab[h * 4096 + 2048 - 512];

  bf16x8 vone;
#pragma unroll
  for (int j = 0; j < 8; ++j) vone[j] = (__bf16)1.0f;

  f32x4 of[2][4] = {};
  f32x4 l_acc[2] = {};  // l via MFMA: rows match of[] layout, cols redundant

  auto stage = [&](int kt, int buf) {
    const int k0 = kt * 64;
#pragma unroll
    for (int p = 0; p < 2; ++p) {
      int idx = p * 256 + tid;
      int key = idx >> 3, c = idx & 7;
      int cs = c ^ (key & 7);
      gload_lds16(k_ws + (size_t)(b * 2048 + k0 + key) * 1024 + h * 64 + cs * 8,
                  Klds[buf] + (size_t)(p * 256 + wbase) * 8);
    }
#pragma unroll
    for (int p = 0; p < 2; ++p) {
      int idx = p * 256 + tid;
      int d = idx >> 3, c = idx & 7;
      int cs = c ^ (d & 7);
      gload_lds16(vt_ws + (size_t)(h * 64 + d) * 4096 + b * 2048 + k0 + cs * 8,
                  Vlds[buf] + (size_t)(p * 256 + wbase) * 8);
    }
    const int diff = k0 - q0;
    const bool farr = (diff >= 256) || (diff <= -192);
    if (!farr && tid < 191)
      bias_lds[buf][tid] = bias_tab[h * 4096 + 2048 + k0 - q0 - 127 + tid];
  };

  stage(0, 0);

  for (int kt = 0; kt < 32; ++kt) {
    const int cur = kt & 1;
    const int k0 = kt * 64;
    const int diff = k0 - q0;
    const bool far = (diff >= 256) || (diff <= -192);
    __syncthreads();  // buf[cur] DMA (issued a full compute phase ago) drains here
    if (kt + 1 < 32) stage(kt + 1, cur ^ 1);

    // S^T = K·Q^T + bias (bias as C-init)
    f32x4 st[4][2];
    if (far) {
      const float c0 = (diff > 0) ? bias_far_pos : bias_far_neg;
#pragma unroll
      for (int mt = 0; mt < 4; ++mt)
#pragma unroll
        for (int nt = 0; nt < 2; ++nt)
#pragma unroll
          for (int r = 0; r < 4; ++r) st[mt][nt][r] = c0;
    } else {
#pragma unroll
      for (int mt = 0; mt < 4; ++mt)
#pragma unroll
        for (int nt = 0; nt < 2; ++nt)
#pragma unroll
          for (int r = 0; r < 4; ++r)
            st[mt][nt][r] =
                bias_lds[cur][(mt * 16 + quad * 4 + r) - (wave * 32 + nt * 16 + col) + 127];
    }
#pragma unroll
    for (int ks = 0; ks < 2; ++ks)
#pragma unroll
      for (int mt = 0; mt < 4; ++mt) {
        bf16x8 kf = *(const bf16x8*)(Klds[cur] + (mt * 16 + col) * 64 +
                                     (((ks * 4 + quad) ^ sw) * 8));
        st[mt][0] = __builtin_amdgcn_mfma_f32_16x16x32_bf16(kf, qf[0][ks], st[mt][0], 0, 0, 0);
        st[mt][1] = __builtin_amdgcn_mfma_f32_16x16x32_bf16(kf, qf[1][ks], st[mt][1], 0, 0, 0);
      }

    // p = exp2(st); pack 4 keys -> ds_write_b64 into P[q][key]
#pragma unroll
    for (int nt = 0; nt < 2; ++nt)
#pragma unroll
      for (int mt = 0; mt < 4; ++mt) {
        float p0 = __builtin_amdgcn_exp2f(st[mt][nt][0]);
        float p1 = __builtin_amdgcn_exp2f(st[mt][nt][1]);
        float p2 = __builtin_amdgcn_exp2f(st[mt][nt][2]);
        float p3 = __builtin_amdgcn_exp2f(st[mt][nt][3]);
        ushort4 pk;
        pk.x = bfbits(p0); pk.y = bfbits(p1); pk.z = bfbits(p2); pk.w = bfbits(p3);
        *(ushort4*)(Plds + (wave * 32 + nt * 16 + col) * LDK + mt * 16 + quad * 4) = pk;
      }
    __threadfence_block();  // wave-private strips: compiler+lgkmcnt fence suffices

    // O += P·V ; l += P·1 (same bf16 P for both -> normalization errors cancel)
#pragma unroll
    for (int ks = 0; ks < 2; ++ks) {
      bf16x8 pf0 = *(const bf16x8*)(Plds + (wave * 32 + col) * LDK + ks * 32 + quad * 8);
      bf16x8 pf1 = *(const bf16x8*)(Plds + (wave * 32 + 16 + col) * LDK + ks * 32 + quad * 8);
      l_acc[0] = __builtin_amdgcn_mfma_f32_16x16x32_bf16(pf0, vone, l_acc[0], 0, 0, 0);
      l_acc[1] = __builtin_amdgcn_mfma_f32_16x16x32_bf16(pf1, vone, l_acc[1], 0, 0, 0);
#pragma unroll
      for (int dn = 0; dn < 4; ++dn) {
        bf16x8 vf = *(const bf16x8*)(Vlds[cur] + (dn * 16 + col) * 64 +
                                     (((ks * 4 + quad) ^ sw) * 8));
        of[0][dn] = __builtin_amdgcn_mfma_f32_16x16x32_bf16(pf0, vf, of[0][dn], 0, 0, 0);
        of[1][dn] = __builtin_amdgcn_mfma_f32_16x16x32_bf16(pf1, vf, of[1][dn], 0, 0, 0);
      }
    }
  }

  // epilogue: l_acc rows match of[] rows (no shuffles / LDS / barrier needed)
#pragma unroll
  for (int mtp = 0; mtp < 2; ++mtp)
#pragma unroll
    for (int r = 0; r < 4; ++r) {
      float inv = 1.0f / fmaxf(l_acc[mtp][r], 1e-30f);
      size_t row = (size_t)(b * 2048 + q0 + wave * 32 + mtp * 16 + quad * 4 + r);
#pragma unroll
      for (int dn = 0; dn < 4; ++dn)
        q_ws[row * 1024 + h * 64 + dn * 16 + col] = bfbits(of[mtp][dn][r] * inv);
    }
}

extern "C" void kernel_launch(void* const* d_in, const int* in_sizes, int n_in,
                              void* d_out, int out_size, void* d_ws, size_t ws_size,
                              hipStream_t stream) {
  const float* hidden = (const float*)d_in[0];
  const float* Wq = (const float*)d_in[1];
  const float* Wk = (const float*)d_in[2];
  const float* Wv = (const float*)d_in[3];
  const float* Wo = (const float*)d_in[4];
  const float* rel_emb = (const float*)d_in[5];
  float* out = (float*)d_out;

  unsigned short* q_ws = (unsigned short*)d_ws;  // 8 MB; Q (x log2e), then attn output
  unsigned short* k_ws = q_ws + 4194304;         // 8 MB
  unsigned short* vt_ws = k_ws + 4194304;        // 8 MB, V transposed [h*64+d][token]
  unsigned short* wt_q = vt_ws + 4194304;        // 2 MB Wt[n][k] bf16
  unsigned short* wt_k = wt_q + 1048576;         // 2 MB
  unsigned short* wt_v = wt_k + 1048576;         // 2 MB
  unsigned short* wt_o = wt_v + 1048576;         // 2 MB
  float* bias_tab = (float*)(wt_o + 1048576);    // 256 KB
  unsigned short* hid_bf = (unsigned short*)d_out;

  prelude_kernel<<<3328, 256, 0, stream>>>(hidden, hid_bf, Wq, Wk, Wv, Wo,
                                           wt_q, wt_k, wt_v, wt_o, rel_emb, bias_tab);
  gemm_kernel<false, 128><<<dim3(24, 32), 256, 0, stream>>>(
      hid_bf, wt_q, wt_k, wt_v, q_ws, k_ws, vt_ws, LOG2E);
  attn_kernel<<<dim3(16, 32), 256, 0, stream>>>(q_ws, k_ws, vt_ws, bias_tab);
  gemm_kernel<true, 64><<<dim3(16, 32), 256, 0, stream>>>(
      q_ws, wt_o, wt_o, wt_o, out, out, out, 1.0f);
}